// Round 1
// baseline (10095.737 us; speedup 1.0000x reference)
//
#include <hip/hip_runtime.h>
#include <hip/hip_cooperative_groups.h>

namespace cg = cooperative_groups;

#define NN    4096
#define TT    300
#define TPAD  320          // 16 t-chunks * 20
#define TCH   20
#define GRID  256
#define BLOCK 1024
#define DECAYF 0.9900498337491681f   // expf(-1/100)
#define THRESHF 10.0f

// ws layout: inpT [NN][TPAD] | X [TPAD][NN] | masks [2][256] u32 (16 bits used)
#define WS_REQ ((size_t)NN*TPAD*4*2 + 2048)

__global__ __launch_bounds__(BLOCK, 4)
void lif_sim(const int* __restrict__ inp, const float* __restrict__ w,
             const float* __restrict__ w_rec, float* __restrict__ out,
             float* __restrict__ ws)
{
    float* inpT = ws;                                    // [NN][TPAD]
    float* X    = ws + (size_t)NN * TPAD;                // [TPAD][NN]
    unsigned int* masks = (unsigned int*)(X + (size_t)TPAD * NN); // [2][256]

    float* s_all = out;
    float* t_all = out + (size_t)TT * NN;
    float* v_all = out + (size_t)2 * TT * NN;

    cg::grid_group grid = cg::this_grid();
    const int tid  = threadIdx.x;
    const int bid  = blockIdx.x;
    const int gtid = bid * BLOCK + tid;

    __shared__ float smem[10240];   // 40 KB: phase1 [4][10][256], phase2 red[64][17]

    // ---------- phase 0: zero masks, build padded transpose inpT ----------
    if (gtid < 512) masks[gtid] = 0u;                    // both parities
    if (gtid < NN * 32) {                                // zero pad cols t in [300,320)
        int j = gtid >> 5, tl = gtid & 31;
        if (tl < TPAD - TT) inpT[(size_t)j * TPAD + TT + tl] = 0.0f;
    }
    for (int idx = gtid; idx < TT * NN; idx += GRID * BLOCK) {
        int t = idx >> 12, j = idx & (NN - 1);           // inp row-major [T][N]
        inpT[(size_t)j * TPAD + t] = (float)inp[idx];
    }
    grid.sync();

    // ---------- phase 1: X = inp @ w (fp32, deterministic 4-way j-split) ----------
    {
        const int ct  = bid >> 4;                 // t-chunk 0..15
        const int cc  = bid & 15;                 // col-chunk 0..15
        const int c1  = tid & 255;                // col within chunk
        const int jp  = tid >> 8;                 // j-part 0..3
        const int col = cc * 256 + c1;
        const int t0  = ct * TCH;
        const int j0  = jp * 1024;
        const float* wp = w + col;
#pragma unroll
        for (int half = 0; half < 2; ++half) {
            const int th0 = t0 + 10 * half;
            float acc[10];
#pragma unroll
            for (int k = 0; k < 10; ++k) acc[k] = 0.0f;
            for (int j = j0; j < j0 + 1024; ++j) {
                float wj = wp[(size_t)j * NN];                    // vector op
                const float* iprow = inpT + (size_t)j * TPAD + th0; // uniform -> s_load
#pragma unroll
                for (int k = 0; k < 10; ++k) acc[k] = fmaf(iprow[k], wj, acc[k]);
            }
#pragma unroll
            for (int k = 0; k < 10; ++k) smem[(jp * 10 + k) * 256 + c1] = acc[k];
            __syncthreads();
            if (jp == 0) {
#pragma unroll
                for (int k = 0; k < 10; ++k) {
                    float s = smem[k * 256 + c1] + smem[(10 + k) * 256 + c1]
                            + smem[(20 + k) * 256 + c1] + smem[(30 + k) * 256 + c1];
                    X[(size_t)(th0 + k) * NN + col] = s;
                }
            }
            __syncthreads();
        }
    }
    grid.sync();

    // ---------- phase 2: 300 sequential LIF steps ----------
    // block owns cols [16*bid, 16*bid+16); thread (c = tid&15, r = tid>>4) gathers
    // rows [64r, 64r+64) of w_rec for col c.  Spike masks: u32 word per block,
    // low 16 bits, double-buffered by t parity.
    const int c   = tid & 15;
    const int r   = tid >> 4;                     // 0..63
    const int col = bid * 16 + c;

    float v = 0.0f, tv = 1.0f;
    int sprev = 0;

    const float* wrc = w_rec + col + (size_t)(r << 6) * NN;

    for (int t = 0; t < TT; ++t) {
        const unsigned int* mk = masks + (t & 1) * 256 + (r << 2);
        uint4 q4 = *((const uint4*)mk);
        unsigned long long M = (unsigned long long)q4.x
                             | ((unsigned long long)q4.y << 16)
                             | ((unsigned long long)q4.z << 32)
                             | ((unsigned long long)q4.w << 48);
        float acc0 = 0.0f, acc1 = 0.0f;
        while (M) {                                // uniform per 16-lane group
            int b0 = __builtin_ctzll(M); M &= M - 1;
            float l0 = wrc[(size_t)b0 * NN];
            float l1 = 0.0f;
            if (M) {                               // 2-deep load ILP
                int b1 = __builtin_ctzll(M); M &= M - 1;
                l1 = wrc[(size_t)b1 * NN];
            }
            acc0 += l0; acc1 += l1;
        }
        smem[r * 17 + c] = acc0 + acc1;
        __syncthreads();
        if (tid < 16) {
            float xr = 0.0f;
#pragma unroll
            for (int k = 0; k < 64; ++k) xr += smem[k * 17 + tid];
            float x = X[(size_t)t * NN + col] + xr;
            v *= DECAYF;
            if (sprev) x = 0.0f;                   // refractory gate == spiked last step
            v += x;
            const bool spike = v >= THRESHF;
            if (spike) { tv = (float)t / 300.0f; v = 0.0f; }
            sprev = spike ? 1 : 0;
            size_t o = (size_t)t * NN + col;
            s_all[o] = spike ? 1.0f : 0.0f;
            t_all[o] = tv;
            v_all[o] = v;
            unsigned long long bal = __ballot(spike);
            if (tid == 0)
                masks[((t + 1) & 1) * 256 + bid] = (unsigned int)(bal & 0xFFFFull);
        }
        grid.sync();   // barrier + agent-scope fences: publishes masks across XCDs
    }
}

extern "C" void kernel_launch(void* const* d_in, const int* in_sizes, int n_in,
                              void* d_out, int out_size, void* d_ws, size_t ws_size,
                              hipStream_t stream) {
    if (ws_size < WS_REQ) return;   // need ~10 MB scratch
    const int*   inp   = (const int*)d_in[0];
    const float* w     = (const float*)d_in[1];
    const float* w_rec = (const float*)d_in[2];
    float* out = (float*)d_out;
    float* ws  = (float*)d_ws;
    void* args[] = {(void*)&inp, (void*)&w, (void*)&w_rec, (void*)&out, (void*)&ws};
    hipLaunchCooperativeKernel((const void*)lif_sim, dim3(GRID), dim3(BLOCK),
                               args, 0, stream);
}

// Round 2
// 2715.831 us; speedup vs baseline: 3.7174x; 3.7174x over previous
//
#include <hip/hip_runtime.h>
#include <hip/hip_cooperative_groups.h>

namespace cg = cooperative_groups;

#define NN    4096
#define TT    300
#define TPAD  320          // 16 t-chunks * 20
#define TCH   20
#define GRID  256
#define BLOCK 1024
#define DECAYF 0.9900498337491681f   // expf(-1/100)
#define THRESHF 10.0f

// ws layout: inpT [NN][TPAD] | X [TPAD][NN] | maskbuf [2][256] u32 (tag<<16 | mask16)
#define WS_REQ ((size_t)NN*TPAD*4*2 + 2048)

__global__ __launch_bounds__(BLOCK, 4)
void lif_sim(const int* __restrict__ inp, const float* __restrict__ w,
             const float* __restrict__ w_rec, float* __restrict__ out,
             float* __restrict__ ws)
{
    float* inpT = ws;                                    // [NN][TPAD]
    float* X    = ws + (size_t)NN * TPAD;                // [TPAD][NN]
    unsigned int* maskbuf = (unsigned int*)(X + (size_t)TPAD * NN); // [2][256]

    float* s_all = out;
    float* t_all = out + (size_t)TT * NN;
    float* v_all = out + (size_t)2 * TT * NN;

    cg::grid_group grid = cg::this_grid();
    const int tid  = threadIdx.x;
    const int bid  = blockIdx.x;
    const int gtid = bid * BLOCK + tid;

    __shared__ float smem[10240];            // phase1 [4][10][256]; phase2 partials [64][17]
    __shared__ unsigned int mask_sh[256];

    // ---------- phase 0: zero mask slots (both parities), build padded transpose ----------
    if (gtid < 512) maskbuf[gtid] = 0u;      // tag 0, payload 0 == valid step-0 input
    if (gtid < NN * 32) {                    // zero pad cols t in [300,320)
        int j = gtid >> 5, tl = gtid & 31;
        if (tl < TPAD - TT) inpT[(size_t)j * TPAD + TT + tl] = 0.0f;
    }
    for (int idx = gtid; idx < TT * NN; idx += GRID * BLOCK) {
        int t = idx >> 12, j = idx & (NN - 1);           // inp row-major [T][N]
        inpT[(size_t)j * TPAD + t] = (float)inp[idx];
    }
    grid.sync();

    // ---------- phase 1: X = inp @ w (fp32, deterministic 4-way j-split) ----------
    {
        const int ct  = bid >> 4;                 // t-chunk 0..15
        const int cc  = bid & 15;                 // col-chunk 0..15
        const int c1  = tid & 255;                // col within chunk
        const int jp  = tid >> 8;                 // j-part 0..3
        const int col = cc * 256 + c1;
        const int t0  = ct * TCH;
        const int j0  = jp * 1024;
        const float* wp = w + col;
#pragma unroll
        for (int half = 0; half < 2; ++half) {
            const int th0 = t0 + 10 * half;
            float acc[10];
#pragma unroll
            for (int k = 0; k < 10; ++k) acc[k] = 0.0f;
            for (int j = j0; j < j0 + 1024; ++j) {
                float wj = wp[(size_t)j * NN];                      // vector load
                const float* iprow = inpT + (size_t)j * TPAD + th0; // uniform -> s_load
#pragma unroll
                for (int k = 0; k < 10; ++k) acc[k] = fmaf(iprow[k], wj, acc[k]);
            }
#pragma unroll
            for (int k = 0; k < 10; ++k) smem[(jp * 10 + k) * 256 + c1] = acc[k];
            __syncthreads();
            if (jp == 0) {
#pragma unroll
                for (int k = 0; k < 10; ++k) {
                    float s = smem[k * 256 + c1] + smem[(10 + k) * 256 + c1]
                            + smem[(20 + k) * 256 + c1] + smem[(30 + k) * 256 + c1];
                    X[(size_t)(th0 + k) * NN + col] = s;
                }
            }
            __syncthreads();
        }
    }
    grid.sync();

    // ---------- phase 2: 300 sequential LIF steps, data-flow sync (no grid.sync) ----------
    // Block owns cols [16*bid, 16*bid+16); thread (c = tid&15, r = tid>>4) gathers
    // rows [64r, 64r+64) of w_rec for col c.  Publication k (k=1..300) of block b's
    // 16-bit spike mask goes to maskbuf[k&1][b] as (k<<16)|mask — step t consumes
    // publication k==t (k=0 is the phase-0 zeros).  Double-buffer is race-free:
    // a block reaches publication k+2 only after every block consumed publication k.
    const int c   = tid & 15;
    const int r   = tid >> 4;                     // 0..63
    const int col = bid * 16 + c;

    float v = 0.0f, tv = 1.0f;
    int sprev = 0;
    const float* wrc = w_rec + col + (size_t)(r << 6) * NN;

    float xreg = 0.0f;
    if (tid < 16) xreg = X[col];                  // X[t=0][col], valid after grid.sync

    for (int t = 0; t < TT; ++t) {
        // stage 1: acquire all 256 masks of publication t (relaxed agent atomics: no L2 flush)
        if (tid < 256) {
            unsigned int* p = maskbuf + (t & 1) * 256 + tid;
            unsigned int word;
            while (((word = __hip_atomic_load(p, __ATOMIC_RELAXED,
                                              __HIP_MEMORY_SCOPE_AGENT)) >> 16)
                   != (unsigned int)t) {}
            mask_sh[tid] = word & 0xFFFFu;
        }
        __syncthreads();

        // stage 2: sparse row-gather of w_rec (4-deep load ILP)
        unsigned long long M;
        {
            const unsigned int* ms = mask_sh + (r << 2);
            M = (unsigned long long)ms[0]        | ((unsigned long long)ms[1] << 16)
              | ((unsigned long long)ms[2] << 32) | ((unsigned long long)ms[3] << 48);
        }
        float acc0 = 0.0f, acc1 = 0.0f;
        while (M) {
            float l0, l1 = 0.0f, l2 = 0.0f, l3 = 0.0f;
            int b0 = __builtin_ctzll(M); M &= M - 1;
            l0 = wrc[(size_t)b0 * NN];
            if (M) { int b = __builtin_ctzll(M); M &= M - 1; l1 = wrc[(size_t)b * NN]; }
            if (M) { int b = __builtin_ctzll(M); M &= M - 1; l2 = wrc[(size_t)b * NN]; }
            if (M) { int b = __builtin_ctzll(M); M &= M - 1; l3 = wrc[(size_t)b * NN]; }
            acc0 += l0 + l2; acc1 += l1 + l3;
        }
        smem[r * 17 + c] = acc0 + acc1;
        __syncthreads();

        // stage 3: wave0 reduces 64 partials/col via shuffle, runs LIF, publishes mask
        if (tid < 64) {
            const int cw = tid & 15, q = tid >> 4;
            float part = 0.0f;
            const float* sp = smem + q * 16 * 17 + cw;
#pragma unroll
            for (int k = 0; k < 16; ++k) part += sp[k * 17];
            part += __shfl_xor(part, 16, 64);
            part += __shfl_xor(part, 32, 64);

            bool spike = false;
            if (tid < 16) {
                float x = xreg + part;
                v *= DECAYF;
                if (sprev) x = 0.0f;              // refractory == spiked last step
                v += x;
                spike = v >= THRESHF;
                if (spike) { tv = (float)t * (1.0f / 300.0f); v = 0.0f; }
                sprev = spike ? 1 : 0;
            }
            unsigned long long bal = __ballot(spike);
            if (tid == 0) {
                unsigned int word = ((unsigned int)(t + 1) << 16)
                                  | (unsigned int)(bal & 0xFFFFull);
                __hip_atomic_store(maskbuf + ((t + 1) & 1) * 256 + bid, word,
                                   __ATOMIC_RELAXED, __HIP_MEMORY_SCOPE_AGENT);
            }
            if (tid < 16) {
                size_t o = (size_t)t * NN + col;
                s_all[o] = spike ? 1.0f : 0.0f;
                t_all[o] = tv;
                v_all[o] = v;
                if (t + 1 < TT) xreg = X[(size_t)(t + 1) * NN + col];  // off critical path
            }
        }
        // no barrier needed here: stage-1 spin of t+1 can't complete until every
        // block (incl. ours) publishes t+1, and our wave0 does that above; smem
        // partials of t+1 are written only after the stage-1 __syncthreads.
    }
}

extern "C" void kernel_launch(void* const* d_in, const int* in_sizes, int n_in,
                              void* d_out, int out_size, void* d_ws, size_t ws_size,
                              hipStream_t stream) {
    if (ws_size < WS_REQ) return;   // need ~10 MB scratch
    const int*   inp   = (const int*)d_in[0];
    const float* w     = (const float*)d_in[1];
    const float* w_rec = (const float*)d_in[2];
    float* out = (float*)d_out;
    float* ws  = (float*)d_ws;
    void* args[] = {(void*)&inp, (void*)&w, (void*)&w_rec, (void*)&out, (void*)&ws};
    hipLaunchCooperativeKernel((const void*)lif_sim, dim3(GRID), dim3(BLOCK),
                               args, 0, stream);
}

// Round 3
// 2618.086 us; speedup vs baseline: 3.8562x; 1.0373x over previous
//
#include <hip/hip_runtime.h>
#include <hip/hip_cooperative_groups.h>

namespace cg = cooperative_groups;

#define NN    4096
#define TT    300
#define TPAD  320          // 16 t-chunks * 20
#define TCH   20
#define GRID  256
#define BLOCK 1024
#define DECAYF 0.9900498337491681f   // expf(-1/100)
#define THRESHF 10.0f

// ws: inpT [NN][TPAD] | X [TPAD][NN] | maskbuf [2][256] u32 ((t+1)<<16|mask16) | cnt u32
#define WS_REQ ((size_t)NN*TPAD*4*2 + 2048)

__global__ __launch_bounds__(BLOCK, 4)
void lif_sim(const int* __restrict__ inp, const float* __restrict__ w,
             const float* __restrict__ w_rec, float* __restrict__ out,
             float* __restrict__ ws)
{
    float* inpT = ws;                                    // [NN][TPAD]
    float* X    = ws + (size_t)NN * TPAD;                // [TPAD][NN]
    unsigned int* maskbuf = (unsigned int*)(X + (size_t)TPAD * NN); // [2][256]
    unsigned int* cnt     = maskbuf + 512;               // monotonic publication counter

    float* s_all = out;
    float* t_all = out + (size_t)TT * NN;
    float* v_all = out + (size_t)2 * TT * NN;

    cg::grid_group grid = cg::this_grid();
    const int tid  = threadIdx.x;
    const int bid  = blockIdx.x;
    const int gtid = bid * BLOCK + tid;

    __shared__ float smem[10240];            // phase1 [4][10][256]; phase2 partials [64][17]
    __shared__ unsigned int mask_sh[256];

    // ---------- phase 0: zero masks+counter, build padded transpose inpT ----------
    if (gtid < 513) maskbuf[gtid] = 0u;      // publication 0 (tag 0, no spikes) + cnt=0
    if (gtid < NN * 32) {                    // zero pad cols t in [300,320)
        int j = gtid >> 5, tl = gtid & 31;
        if (tl < TPAD - TT) inpT[(size_t)j * TPAD + TT + tl] = 0.0f;
    }
    for (int idx = gtid; idx < TT * NN; idx += GRID * BLOCK) {
        int t = idx >> 12, j = idx & (NN - 1);           // inp row-major [T][N]
        inpT[(size_t)j * TPAD + t] = (float)inp[idx];
    }
    grid.sync();

    // ---------- phase 1: X = inp @ w (fp32, one j-pass, 20 accumulators) ----------
    {
        const int ct  = bid >> 4;                 // t-chunk 0..15
        const int cc  = bid & 15;                 // col-chunk 0..15
        const int c1  = tid & 255;                // col within chunk
        const int jp  = tid >> 8;                 // j-part 0..3
        const int col = cc * 256 + c1;
        const int t0  = ct * TCH;
        const int j0  = jp * 1024;
        const float* wp = w + col;
        float acc[20];
#pragma unroll
        for (int k = 0; k < 20; ++k) acc[k] = 0.0f;
        for (int j = j0; j < j0 + 1024; ++j) {
            float wj = wp[(size_t)j * NN];                     // coalesced vector load
            const float* iprow = inpT + (size_t)j * TPAD + t0; // uniform -> s_load
#pragma unroll
            for (int k = 0; k < 20; ++k) acc[k] = fmaf(iprow[k], wj, acc[k]);
        }
#pragma unroll
        for (int half = 0; half < 2; ++half) {
#pragma unroll
            for (int k = 0; k < 10; ++k) smem[(jp * 10 + k) * 256 + c1] = acc[half * 10 + k];
            __syncthreads();
            if (jp == 0) {
#pragma unroll
                for (int k = 0; k < 10; ++k) {
                    float s = smem[k * 256 + c1] + smem[(10 + k) * 256 + c1]
                            + smem[(20 + k) * 256 + c1] + smem[(30 + k) * 256 + c1];
                    X[(size_t)(t0 + half * 10 + k) * NN + col] = s;
                }
            }
            __syncthreads();
        }
    }
    grid.sync();

    // ---------- phase 2: 300 sequential LIF steps ----------
    // Readiness: single monotonic counter; publisher k does {mask store (sc1);
    // s_waitcnt 0; fetch_add} — hand-rolled release, no L2 writeback/invalidate.
    // Consumer: thread 0 spins cnt >= 256*t, barrier, then ONE coalesced one-shot
    // read of the 256 mask words (16 line-reads/block = floor). Tags in the words
    // are belt-and-braces (re-spin only if stale).
    const int c   = tid & 15;
    const int r   = tid >> 4;                     // 0..63
    const int col = bid * 16 + c;

    float v = 0.0f, tv = 1.0f;
    int sprev = 0;
    const float* wrc = w_rec + col + (size_t)(r << 6) * NN;

    float xreg = 0.0f;
    if (tid < 16) xreg = X[col];                  // X[t=0][col]

    for (int t = 0; t < TT; ++t) {
        if (tid == 0 && t > 0) {
            while (__hip_atomic_load(cnt, __ATOMIC_RELAXED, __HIP_MEMORY_SCOPE_AGENT)
                   < 256u * (unsigned int)t) {}
        }
        __syncthreads();                          // broadcast readiness
        if (tid < 256) {
            unsigned int* p = maskbuf + (t & 1) * 256 + tid;
            unsigned int word = __hip_atomic_load(p, __ATOMIC_RELAXED,
                                                  __HIP_MEMORY_SCOPE_AGENT);
            while ((word >> 16) != (unsigned int)t)          // should never loop
                word = __hip_atomic_load(p, __ATOMIC_RELAXED,
                                         __HIP_MEMORY_SCOPE_AGENT);
            mask_sh[tid] = word & 0xFFFFu;
        }
        __syncthreads();

        // sparse row-gather of w_rec, 8-deep load ILP
        unsigned long long M;
        {
            const unsigned int* ms = mask_sh + (r << 2);
            M = (unsigned long long)ms[0]         | ((unsigned long long)ms[1] << 16)
              | ((unsigned long long)ms[2] << 32) | ((unsigned long long)ms[3] << 48);
        }
        float acc0 = 0.0f, acc1 = 0.0f, acc2 = 0.0f, acc3 = 0.0f;
        while (M) {
            float l0, l1 = 0.0f, l2 = 0.0f, l3 = 0.0f,
                  l4 = 0.0f, l5 = 0.0f, l6 = 0.0f, l7 = 0.0f;
            int b0 = __builtin_ctzll(M); M &= M - 1;
            l0 = wrc[(size_t)b0 * NN];
            if (M) { int b = __builtin_ctzll(M); M &= M - 1; l1 = wrc[(size_t)b * NN]; }
            if (M) { int b = __builtin_ctzll(M); M &= M - 1; l2 = wrc[(size_t)b * NN]; }
            if (M) { int b = __builtin_ctzll(M); M &= M - 1; l3 = wrc[(size_t)b * NN]; }
            if (M) { int b = __builtin_ctzll(M); M &= M - 1; l4 = wrc[(size_t)b * NN]; }
            if (M) { int b = __builtin_ctzll(M); M &= M - 1; l5 = wrc[(size_t)b * NN]; }
            if (M) { int b = __builtin_ctzll(M); M &= M - 1; l6 = wrc[(size_t)b * NN]; }
            if (M) { int b = __builtin_ctzll(M); M &= M - 1; l7 = wrc[(size_t)b * NN]; }
            acc0 += l0 + l4; acc1 += l1 + l5; acc2 += l2 + l6; acc3 += l3 + l7;
        }
        smem[r * 17 + c] = (acc0 + acc1) + (acc2 + acc3);
        __syncthreads();

        // wave0: reduce 64 partials/col, LIF, publish, store outputs
        if (tid < 64) {
            const int cw = tid & 15, q = tid >> 4;
            float part = 0.0f;
            const float* sp = smem + q * 16 * 17 + cw;
#pragma unroll
            for (int k = 0; k < 16; ++k) part += sp[k * 17];
            part += __shfl_xor(part, 16, 64);
            part += __shfl_xor(part, 32, 64);

            bool spike = false;
            if (tid < 16) {
                float x = xreg + part;
                v *= DECAYF;
                if (sprev) x = 0.0f;              // refractory == spiked last step
                v += x;
                spike = v >= THRESHF;
                if (spike) { tv = (float)t * (1.0f / 300.0f); v = 0.0f; }
                sprev = spike ? 1 : 0;
            }
            unsigned long long bal = __ballot(spike);
            if (tid == 0) {
                unsigned int word = ((unsigned int)(t + 1) << 16)
                                  | (unsigned int)(bal & 0xFFFFull);
                __hip_atomic_store(maskbuf + ((t + 1) & 1) * 256 + bid, word,
                                   __ATOMIC_RELAXED, __HIP_MEMORY_SCOPE_AGENT);
                __builtin_amdgcn_s_waitcnt(0);    // mask store acked at LLC
                __hip_atomic_fetch_add(cnt, 1u, __ATOMIC_RELAXED,
                                       __HIP_MEMORY_SCOPE_AGENT);
            }
            if (tid < 16) {
                size_t o = (size_t)t * NN + col;
                s_all[o] = spike ? 1.0f : 0.0f;
                t_all[o] = tv;
                v_all[o] = v;
                if (t + 1 < TT) xreg = X[(size_t)(t + 1) * NN + col];  // off critical path
            }
        }
        // no trailing barrier: step t+1's mask consumption is gated by the counter,
        // and this block's own smem partial writes for t+1 are after the barriers above.
    }
}

extern "C" void kernel_launch(void* const* d_in, const int* in_sizes, int n_in,
                              void* d_out, int out_size, void* d_ws, size_t ws_size,
                              hipStream_t stream) {
    if (ws_size < WS_REQ) return;   // need ~10 MB scratch
    const int*   inp   = (const int*)d_in[0];
    const float* w     = (const float*)d_in[1];
    const float* w_rec = (const float*)d_in[2];
    float* out = (float*)d_out;
    float* ws  = (float*)d_ws;
    void* args[] = {(void*)&inp, (void*)&w, (void*)&w_rec, (void*)&out, (void*)&ws};
    hipLaunchCooperativeKernel((const void*)lif_sim, dim3(GRID), dim3(BLOCK),
                               args, 0, stream);
}

// Round 4
// 2290.969 us; speedup vs baseline: 4.4068x; 1.1428x over previous
//
#include <hip/hip_runtime.h>
#include <hip/hip_cooperative_groups.h>

namespace cg = cooperative_groups;

#define NN    4096
#define TT    300
#define TPAD  320          // 16 t-chunks * 20
#define TCH   20
#define GRID  256
#define BLOCK 1024
#define NREP  16           // mask replicas (16 blocks per replica)
#define DECAYF 0.9900498337491681f   // expf(-1/100)
#define THRESHF 10.0f

// ws: inpT [NN][TPAD] | X [TPAD][NN] | maskrep [NREP][2][256] u32 ((t)<<16|mask16)
#define WS_REQ ((size_t)NN*TPAD*4*2 + 40960)

__global__ __launch_bounds__(BLOCK, 4)
void lif_sim(const int* __restrict__ inp, const float* __restrict__ w,
             const float* __restrict__ w_rec, float* __restrict__ out,
             float* __restrict__ ws)
{
    float* inpT = ws;                                    // [NN][TPAD]
    float* X    = ws + (size_t)NN * TPAD;                // [TPAD][NN]
    unsigned int* maskrep = (unsigned int*)(X + (size_t)TPAD * NN); // [NREP][2][256]

    float* s_all = out;
    float* t_all = out + (size_t)TT * NN;
    float* v_all = out + (size_t)2 * TT * NN;

    cg::grid_group grid = cg::this_grid();
    const int tid  = threadIdx.x;
    const int bid  = blockIdx.x;
    const int gtid = bid * BLOCK + tid;

    __shared__ float smem[10240];            // phase1 [4][10][256]; phase2 partials [64][17]

    // ---------- phase 0: zero all mask replicas, build padded transpose inpT ----------
    if (gtid < NREP * 2 * 256) maskrep[gtid] = 0u;   // tag 0 == valid step-0 input (no spikes)
    if (gtid < NN * 32) {                    // zero pad cols t in [300,320)
        int j = gtid >> 5, tl = gtid & 31;
        if (tl < TPAD - TT) inpT[(size_t)j * TPAD + TT + tl] = 0.0f;
    }
    for (int idx = gtid; idx < TT * NN; idx += GRID * BLOCK) {
        int t = idx >> 12, j = idx & (NN - 1);           // inp row-major [T][N]
        inpT[(size_t)j * TPAD + t] = (float)inp[idx];
    }
    grid.sync();

    // ---------- phase 1: X = inp @ w (fp32, one j-pass, 20 accumulators) ----------
    {
        const int ct  = bid >> 4;                 // t-chunk 0..15
        const int cc  = bid & 15;                 // col-chunk 0..15
        const int c1  = tid & 255;                // col within chunk
        const int jp  = tid >> 8;                 // j-part 0..3
        const int col = cc * 256 + c1;
        const int t0  = ct * TCH;
        const int j0  = jp * 1024;
        const float* wp = w + col;
        float acc[20];
#pragma unroll
        for (int k = 0; k < 20; ++k) acc[k] = 0.0f;
        for (int j = j0; j < j0 + 1024; ++j) {
            float wj = wp[(size_t)j * NN];                     // coalesced vector load
            const float* iprow = inpT + (size_t)j * TPAD + t0; // uniform -> s_load
#pragma unroll
            for (int k = 0; k < 20; ++k) acc[k] = fmaf(iprow[k], wj, acc[k]);
        }
#pragma unroll
        for (int half = 0; half < 2; ++half) {
#pragma unroll
            for (int k = 0; k < 10; ++k) smem[(jp * 10 + k) * 256 + c1] = acc[half * 10 + k];
            __syncthreads();
            if (jp == 0) {
#pragma unroll
                for (int k = 0; k < 10; ++k) {
                    float s = smem[k * 256 + c1] + smem[(10 + k) * 256 + c1]
                            + smem[(20 + k) * 256 + c1] + smem[(30 + k) * 256 + c1];
                    X[(size_t)(t0 + half * 10 + k) * NN + col] = s;
                }
            }
            __syncthreads();
        }
    }
    grid.sync();

    // ---------- phase 2: 300 sequential LIF steps ----------
    // Sync: NO counter, NO broadcast stage. Each thread spins directly on the 4
    // tagged mask words it needs (blocks 4r..4r+3) in replica bid&15; 16-lane
    // groups coalesce to one request/word. Publisher writes its word to all 16
    // replicas (fan-out per LLC line: 16 readers instead of 256).
    // Safety: block b publishes t+1 only after barrier A, which joins ALL its
    // threads' polls — collectively covering all 256 words at tag t. So every
    // block published t => every block finished consuming t-1 => overwriting
    // the (t+1)&1 parity slot (previously tag t-1) is race-free.
    const int c   = tid & 15;
    const int r   = tid >> 4;                     // 0..63
    const int col = bid * 16 + c;

    float v = 0.0f, tv = 1.0f;
    int sprev = 0;
    const float* wrc = w_rec + col + (size_t)(r << 6) * NN;
    const unsigned int* myrep = maskrep + ((bid & 15) * 2) * 256 + (r << 2);

    float xreg = 0.0f;
    if (tid < 16) xreg = X[col];                  // X[t=0][col]

    for (int t = 0; t < TT; ++t) {
        // spin: 4 needed words at tag t (one LLC round trip per poll iteration)
        const unsigned int* p = myrep + (t & 1) * 256;
        unsigned int w0, w1, w2, w3;
        const unsigned int ut = (unsigned int)t;
        for (;;) {
            w0 = __hip_atomic_load(p + 0, __ATOMIC_RELAXED, __HIP_MEMORY_SCOPE_AGENT);
            w1 = __hip_atomic_load(p + 1, __ATOMIC_RELAXED, __HIP_MEMORY_SCOPE_AGENT);
            w2 = __hip_atomic_load(p + 2, __ATOMIC_RELAXED, __HIP_MEMORY_SCOPE_AGENT);
            w3 = __hip_atomic_load(p + 3, __ATOMIC_RELAXED, __HIP_MEMORY_SCOPE_AGENT);
            if ((((w0 >> 16) ^ ut) | ((w1 >> 16) ^ ut)
               | ((w2 >> 16) ^ ut) | ((w3 >> 16) ^ ut)) == 0u) break;
        }
        unsigned long long M = (unsigned long long)(w0 & 0xFFFFu)
                             | ((unsigned long long)(w1 & 0xFFFFu) << 16)
                             | ((unsigned long long)(w2 & 0xFFFFu) << 32)
                             | ((unsigned long long)(w3 & 0xFFFFu) << 48);

        // sparse row-gather of w_rec, 8-deep load ILP
        float acc0 = 0.0f, acc1 = 0.0f, acc2 = 0.0f, acc3 = 0.0f;
        while (M) {
            float l0, l1 = 0.0f, l2 = 0.0f, l3 = 0.0f,
                  l4 = 0.0f, l5 = 0.0f, l6 = 0.0f, l7 = 0.0f;
            int b0 = __builtin_ctzll(M); M &= M - 1;
            l0 = wrc[(size_t)b0 * NN];
            if (M) { int b = __builtin_ctzll(M); M &= M - 1; l1 = wrc[(size_t)b * NN]; }
            if (M) { int b = __builtin_ctzll(M); M &= M - 1; l2 = wrc[(size_t)b * NN]; }
            if (M) { int b = __builtin_ctzll(M); M &= M - 1; l3 = wrc[(size_t)b * NN]; }
            if (M) { int b = __builtin_ctzll(M); M &= M - 1; l4 = wrc[(size_t)b * NN]; }
            if (M) { int b = __builtin_ctzll(M); M &= M - 1; l5 = wrc[(size_t)b * NN]; }
            if (M) { int b = __builtin_ctzll(M); M &= M - 1; l6 = wrc[(size_t)b * NN]; }
            if (M) { int b = __builtin_ctzll(M); M &= M - 1; l7 = wrc[(size_t)b * NN]; }
            acc0 += l0 + l4; acc1 += l1 + l5; acc2 += l2 + l6; acc3 += l3 + l7;
        }
        smem[r * 17 + c] = (acc0 + acc1) + (acc2 + acc3);
        __syncthreads();                          // A: all partials in, all polls done

        float part = 0.0f;
        if (tid < 64) {
            const int cw = tid & 15, q = tid >> 4;
            const float* sp = smem + q * 16 * 17 + cw;
#pragma unroll
            for (int k = 0; k < 16; ++k) part += sp[k * 17];
            part += __shfl_xor(part, 16, 64);
            part += __shfl_xor(part, 32, 64);
        }
        __syncthreads();                          // B: wave0 done with smem; others may
                                                  // race ahead into step t+1 safely
        if (tid < 64) {
            bool spike = false;
            if (tid < 16) {
                float x = xreg + part;
                v *= DECAYF;
                if (sprev) x = 0.0f;              // refractory == spiked last step
                v += x;
                spike = v >= THRESHF;
                if (spike) { tv = (float)t * (1.0f / 300.0f); v = 0.0f; }
                sprev = spike ? 1 : 0;
            }
            unsigned long long bal = __ballot(spike);
            if (tid == 0) {
                unsigned int word = ((unsigned int)(t + 1) << 16)
                                  | (unsigned int)(bal & 0xFFFFull);
                const int par = (t + 1) & 1;
#pragma unroll
                for (int rep = 0; rep < NREP; ++rep)
                    __hip_atomic_store(maskrep + (rep * 2 + par) * 256 + bid, word,
                                       __ATOMIC_RELAXED, __HIP_MEMORY_SCOPE_AGENT);
            }
            if (tid < 16) {
                size_t o = (size_t)t * NN + col;
                s_all[o] = spike ? 1.0f : 0.0f;
                t_all[o] = tv;
                v_all[o] = v;
                if (t + 1 < TT) xreg = X[(size_t)(t + 1) * NN + col];  // off critical path
            }
        }
    }
}

extern "C" void kernel_launch(void* const* d_in, const int* in_sizes, int n_in,
                              void* d_out, int out_size, void* d_ws, size_t ws_size,
                              hipStream_t stream) {
    if (ws_size < WS_REQ) return;   // need ~10.5 MB scratch
    const int*   inp   = (const int*)d_in[0];
    const float* w     = (const float*)d_in[1];
    const float* w_rec = (const float*)d_in[2];
    float* out = (float*)d_out;
    float* ws  = (float*)d_ws;
    void* args[] = {(void*)&inp, (void*)&w, (void*)&w_rec, (void*)&out, (void*)&ws};
    hipLaunchCooperativeKernel((const void*)lif_sim, dim3(GRID), dim3(BLOCK),
                               args, 0, stream);
}

// Round 5
// 1640.032 us; speedup vs baseline: 6.1558x; 1.3969x over previous
//
#include <hip/hip_runtime.h>
#include <hip/hip_cooperative_groups.h>

namespace cg = cooperative_groups;

#define NN    4096
#define TT    300
#define TPAD  320          // 16 t-chunks * 20
#define TCH   20
#define GRID  256
#define BLOCK 1024
#define NREP  16           // mask replicas (16 blocks per replica)
#define DECAYF 0.9900498337491681f   // expf(-1/100)
#define THRESHF 10.0f

// ws: inpT [NN][TPAD] | X [TPAD][NN] | maskrep [NREP][2][256] u32 (t<<16|mask16)
#define WS_REQ ((size_t)NN*TPAD*4*2 + (size_t)NREP*2*256*4)

// Agent-coherent 16B load straight from LLC (bypass L1/L2): sc0 sc1.
__device__ __forceinline__ uint4 llc_load_v4(const uint4* p) {
    uint4 r;
    asm volatile("global_load_dwordx4 %0, %1, off sc0 sc1\n\t"
                 "s_waitcnt vmcnt(0)"
                 : "=v"(r) : "v"(p) : "memory");
    return r;
}

__global__ __launch_bounds__(BLOCK, 4)
void lif_sim(const int* __restrict__ inp, const float* __restrict__ w,
             const float* __restrict__ w_rec, float* __restrict__ out,
             float* __restrict__ ws)
{
    float* inpT = ws;                                    // [NN][TPAD]
    float* X    = ws + (size_t)NN * TPAD;                // [TPAD][NN]
    unsigned int* maskrep = (unsigned int*)(X + (size_t)TPAD * NN); // [NREP][2][256]

    float* s_all = out;
    float* t_all = out + (size_t)TT * NN;
    float* v_all = out + (size_t)2 * TT * NN;

    cg::grid_group grid = cg::this_grid();
    const int tid  = threadIdx.x;
    const int bid  = blockIdx.x;
    const int gtid = bid * BLOCK + tid;

    __shared__ __align__(16) float smem[10240];  // phase1 [4][10][256]
    unsigned int* mask_sh = (unsigned int*)smem; // phase2: [256] raw words
    float*        red_sh  = smem + 256;          // phase2: [16][17] wave partials

    // ---------- phase 0: zero mask replicas, build padded transpose inpT ----------
    if (gtid < NREP * 2 * 256) maskrep[gtid] = 0u;   // tag 0 == valid step-0 (no spikes)
    if (gtid < NN * 32) {                    // zero pad cols t in [300,320)
        int j = gtid >> 5, tl = gtid & 31;
        if (tl < TPAD - TT) inpT[(size_t)j * TPAD + TT + tl] = 0.0f;
    }
    for (int idx = gtid; idx < TT * NN; idx += GRID * BLOCK) {
        int t = idx >> 12, j = idx & (NN - 1);           // inp row-major [T][N]
        inpT[(size_t)j * TPAD + t] = (float)inp[idx];
    }
    grid.sync();

    // ---------- phase 1: X = inp @ w (fp32, one j-pass, 20 accumulators) ----------
    {
        const int ct  = bid >> 4;                 // t-chunk 0..15
        const int cc  = bid & 15;                 // col-chunk 0..15
        const int c1  = tid & 255;                // col within chunk
        const int jp  = tid >> 8;                 // j-part 0..3
        const int col = cc * 256 + c1;
        const int t0  = ct * TCH;
        const int j0  = jp * 1024;
        const float* wp = w + col;
        float acc[20];
#pragma unroll
        for (int k = 0; k < 20; ++k) acc[k] = 0.0f;
        for (int j = j0; j < j0 + 1024; ++j) {
            float wj = wp[(size_t)j * NN];                     // coalesced vector load
            const float* iprow = inpT + (size_t)j * TPAD + t0; // uniform -> s_load
#pragma unroll
            for (int k = 0; k < 20; ++k) acc[k] = fmaf(iprow[k], wj, acc[k]);
        }
#pragma unroll
        for (int half = 0; half < 2; ++half) {
#pragma unroll
            for (int k = 0; k < 10; ++k) smem[(jp * 10 + k) * 256 + c1] = acc[half * 10 + k];
            __syncthreads();
            if (jp == 0) {
#pragma unroll
                for (int k = 0; k < 10; ++k) {
                    float s = smem[k * 256 + c1] + smem[(10 + k) * 256 + c1]
                            + smem[(20 + k) * 256 + c1] + smem[(30 + k) * 256 + c1];
                    X[(size_t)(t0 + half * 10 + k) * NN + col] = s;
                }
            }
            __syncthreads();
        }
    }
    grid.sync();

    // ---------- phase 2: 300 sequential LIF steps ----------
    // Sync: ONLY wave0 polls (64 lanes x dwordx4 = whole 256-word replica, 64
    // requests/iter instead of 256 from 64 groups) -> poll queueing on the mask
    // lines drops ~10x. Detection joined by __all, broadcast via LDS, barrier S.
    // Waves 1..15 idle at S (no memory traffic). Publisher: 16 replica stores.
    // Safety: block b publishes t+1 only after wave0 observed ALL tags t (before
    // S(t)); tag t from block c certifies c consumed t-1 -> overwriting parity
    // slot (t+1)&1 (holding t-1) is race-free.
    const int lane = tid & 63;
    const int wave = tid >> 6;                    // 0..15
    const int c    = tid & 15;
    const int r    = tid >> 4;                    // 0..63 (gather group)
    const int col  = bid * 16 + c;

    float v = 0.0f, tv = 1.0f;
    int sprev = 0;
    const float* wrc = w_rec + col + (size_t)(r << 6) * NN;
    unsigned int* myrep = maskrep + ((bid & 15) * 2) * 256;

    float xreg = 0.0f;
    if (tid < 16) xreg = X[col];                  // X[t=0][col]

    for (int t = 0; t < TT; ++t) {
        // wave0: spin on own replica until all 256 tags == t, then LDS-broadcast
        if (wave == 0) {
            const uint4* pp = (const uint4*)(myrep + (t & 1) * 256) + lane;
            const unsigned int ut = (unsigned int)t;
            uint4 q;
            for (;;) {
                q = llc_load_v4(pp);
                unsigned int bad = ((q.x >> 16) ^ ut) | ((q.y >> 16) ^ ut)
                                 | ((q.z >> 16) ^ ut) | ((q.w >> 16) ^ ut);
                if (__all(bad == 0u)) break;
            }
            ((uint4*)mask_sh)[lane] = q;
        }
        __syncthreads();                          // S: masks ready in LDS

        // sparse row-gather of w_rec, 8-deep load ILP
        unsigned long long M;
        {
            const unsigned int* ms = mask_sh + (r << 2);
            M = ((unsigned long long)(ms[0] & 0xFFFFu))
              | ((unsigned long long)(ms[1] & 0xFFFFu) << 16)
              | ((unsigned long long)(ms[2] & 0xFFFFu) << 32)
              | ((unsigned long long)(ms[3] & 0xFFFFu) << 48);
        }
        float acc0 = 0.0f, acc1 = 0.0f, acc2 = 0.0f, acc3 = 0.0f;
        while (M) {
            float l0, l1 = 0.0f, l2 = 0.0f, l3 = 0.0f,
                  l4 = 0.0f, l5 = 0.0f, l6 = 0.0f, l7 = 0.0f;
            int b0 = __builtin_ctzll(M); M &= M - 1;
            l0 = wrc[(size_t)b0 * NN];
            if (M) { int b = __builtin_ctzll(M); M &= M - 1; l1 = wrc[(size_t)b * NN]; }
            if (M) { int b = __builtin_ctzll(M); M &= M - 1; l2 = wrc[(size_t)b * NN]; }
            if (M) { int b = __builtin_ctzll(M); M &= M - 1; l3 = wrc[(size_t)b * NN]; }
            if (M) { int b = __builtin_ctzll(M); M &= M - 1; l4 = wrc[(size_t)b * NN]; }
            if (M) { int b = __builtin_ctzll(M); M &= M - 1; l5 = wrc[(size_t)b * NN]; }
            if (M) { int b = __builtin_ctzll(M); M &= M - 1; l6 = wrc[(size_t)b * NN]; }
            if (M) { int b = __builtin_ctzll(M); M &= M - 1; l7 = wrc[(size_t)b * NN]; }
            acc0 += l0 + l4; acc1 += l1 + l5; acc2 += l2 + l6; acc3 += l3 + l7;
        }
        // wave-internal pre-reduce across its 4 groups (lanes share c at xor 16/32)
        float part = (acc0 + acc1) + (acc2 + acc3);
        part += __shfl_xor(part, 16, 64);
        part += __shfl_xor(part, 32, 64);
        if (lane < 16) red_sh[wave * 17 + lane] = part;
        __syncthreads();                          // A: 16 wave-partials per col in LDS

        if (wave == 0) {
            const int cw = lane & 15, h = lane >> 4;        // h = 0..3
            const float* sp = red_sh + h * 4 * 17 + cw;
            float s = (sp[0] + sp[17]) + (sp[34] + sp[51]);
            s += __shfl_xor(s, 16, 64);
            s += __shfl_xor(s, 32, 64);

            bool spike = false;
            if (lane < 16) {
                float x = xreg + s;
                v *= DECAYF;
                if (sprev) x = 0.0f;              // refractory == spiked last step
                v += x;
                spike = v >= THRESHF;
                if (spike) { tv = (float)t * (1.0f / 300.0f); v = 0.0f; }
                sprev = spike ? 1 : 0;
            }
            unsigned long long bal = __ballot(spike);
            if (lane == 0) {
                unsigned int word = ((unsigned int)(t + 1) << 16)
                                  | (unsigned int)(bal & 0xFFFFull);
                const int par = (t + 1) & 1;
#pragma unroll
                for (int rep = 0; rep < NREP; ++rep)
                    __hip_atomic_store(maskrep + (rep * 2 + par) * 256 + bid, word,
                                       __ATOMIC_RELAXED, __HIP_MEMORY_SCOPE_AGENT);
            }
            if (lane < 16) {
                size_t o = (size_t)t * NN + col;
                s_all[o] = spike ? 1.0f : 0.0f;
                t_all[o] = tv;
                v_all[o] = v;
                if (t + 1 < TT) xreg = X[(size_t)(t + 1) * NN + col];  // off critical path
            }
        }
        // waves 1..15 proceed to S(t+1) and wait there (no memory traffic)
    }
}

extern "C" void kernel_launch(void* const* d_in, const int* in_sizes, int n_in,
                              void* d_out, int out_size, void* d_ws, size_t ws_size,
                              hipStream_t stream) {
    if (ws_size < WS_REQ) return;   // need ~10.5 MB scratch
    const int*   inp   = (const int*)d_in[0];
    const float* w     = (const float*)d_in[1];
    const float* w_rec = (const float*)d_in[2];
    float* out = (float*)d_out;
    float* ws  = (float*)d_ws;
    void* args[] = {(void*)&inp, (void*)&w, (void*)&w_rec, (void*)&out, (void*)&ws};
    hipLaunchCooperativeKernel((const void*)lif_sim, dim3(GRID), dim3(BLOCK),
                               args, 0, stream);
}

// Round 6
// 1620.656 us; speedup vs baseline: 6.2294x; 1.0120x over previous
//
#include <hip/hip_runtime.h>
#include <hip/hip_cooperative_groups.h>

namespace cg = cooperative_groups;

#define NN    4096
#define TT    300
#define TPAD  320          // 16 t-chunks * 20
#define TCH   20
#define GRID  256
#define BLOCK 1024
#define NREP  16           // mask replicas (16 blocks per replica)
#define WSTRIDE 18         // LDS fp32 row stride (18 floats; coprime-ish banks, 8B align)
#define HROWS 2048         // w_rec rows resident in LDS (fp32)
#define DECAYF 0.9900498337491681f   // expf(-1/100)
#define THRESHF 10.0f

// dynamic LDS: wlds [2048][18] fp32 (144K, reused as phase1 [4][10][256])
//            | mask_sh [256] u32 | red_sh [16][17] f32
#define WLDS_BYTES (HROWS * WSTRIDE * 4)
#define DSM_BYTES  (WLDS_BYTES + 1024 + 16 * 17 * 4)

// ws: inpT [NN][TPAD] | X [TPAD][NN] | maskrep [NREP][2][256] u32 (t<<16|mask16)
#define WS_REQ ((size_t)NN*TPAD*4*2 + (size_t)NREP*2*256*4)

// Agent-coherent 16B load straight from LLC (bypass L1/L2): sc0 sc1.
__device__ __forceinline__ uint4 llc_load_v4(const uint4* p) {
    uint4 r;
    asm volatile("global_load_dwordx4 %0, %1, off sc0 sc1\n\t"
                 "s_waitcnt vmcnt(0)"
                 : "=v"(r) : "v"(p) : "memory");
    return r;
}

__global__ __launch_bounds__(BLOCK, 4)
void lif_sim(const int* __restrict__ inp, const float* __restrict__ w,
             const float* __restrict__ w_rec, float* __restrict__ out,
             float* __restrict__ ws)
{
    float* inpT = ws;                                    // [NN][TPAD]
    float* X    = ws + (size_t)NN * TPAD;                // [TPAD][NN]
    unsigned int* maskrep = (unsigned int*)(X + (size_t)TPAD * NN); // [NREP][2][256]

    float* s_all = out;
    float* t_all = out + (size_t)TT * NN;
    float* v_all = out + (size_t)2 * TT * NN;

    cg::grid_group grid = cg::this_grid();
    const int tid  = threadIdx.x;
    const int bid  = blockIdx.x;
    const int gtid = bid * BLOCK + tid;

    extern __shared__ __align__(16) unsigned char dsm[];
    float*        smem    = (float*)dsm;                       // phase1 [4][10][256]
    float*        wlds    = (float*)dsm;                       // phase2 [2048][18] fp32
    unsigned int* mask_sh = (unsigned int*)(dsm + WLDS_BYTES); // [256]
    float*        red_sh  = (float*)(dsm + WLDS_BYTES + 1024); // [16][17]

    // ---------- phase 0: zero mask replicas, build padded transpose inpT ----------
    if (gtid < NREP * 2 * 256) maskrep[gtid] = 0u;   // tag 0 == valid step-0 (no spikes)
    if (gtid < NN * 32) {                    // zero pad cols t in [300,320)
        int j = gtid >> 5, tl = gtid & 31;
        if (tl < TPAD - TT) inpT[(size_t)j * TPAD + TT + tl] = 0.0f;
    }
    for (int idx = gtid; idx < TT * NN; idx += GRID * BLOCK) {
        int t = idx >> 12, j = idx & (NN - 1);           // inp row-major [T][N]
        inpT[(size_t)j * TPAD + t] = (float)inp[idx];
    }
    grid.sync();

    // ---------- phase 1: X = inp @ w (fp32, one j-pass, 20 accumulators) ----------
    {
        const int ct  = bid >> 4;                 // t-chunk 0..15
        const int cc  = bid & 15;                 // col-chunk 0..15
        const int c1  = tid & 255;                // col within chunk
        const int jp  = tid >> 8;                 // j-part 0..3
        const int col = cc * 256 + c1;
        const int t0  = ct * TCH;
        const int j0  = jp * 1024;
        const float* wp = w + col;
        float acc[20];
#pragma unroll
        for (int k = 0; k < 20; ++k) acc[k] = 0.0f;
        for (int j = j0; j < j0 + 1024; ++j) {
            float wj = wp[(size_t)j * NN];                     // coalesced vector load
            const float* iprow = inpT + (size_t)j * TPAD + t0; // uniform -> s_load
#pragma unroll
            for (int k = 0; k < 20; ++k) acc[k] = fmaf(iprow[k], wj, acc[k]);
        }
#pragma unroll
        for (int half = 0; half < 2; ++half) {
#pragma unroll
            for (int k = 0; k < 10; ++k) smem[(jp * 10 + k) * 256 + c1] = acc[half * 10 + k];
            __syncthreads();
            if (jp == 0) {
#pragma unroll
                for (int k = 0; k < 10; ++k) {
                    float s = smem[k * 256 + c1] + smem[(10 + k) * 256 + c1]
                            + smem[(20 + k) * 256 + c1] + smem[(30 + k) * 256 + c1];
                    X[(size_t)(t0 + half * 10 + k) * NN + col] = s;
                }
            }
            __syncthreads();
        }
    }
    grid.sync();

    // ---------- phase 2 setup ----------
    // Column ownership swizzle: under round-robin dispatch (xcd = bid % 8) each
    // XCD owns a CONTIGUOUS 512-col band -> its 32 blocks' upper-row slices are
    // whole 128B L2 lines totalling exactly 4 MiB = one XCD's L2 (hot across
    // steps). Wrong-mapping risk is perf-only.
    const int colgrp = ((bid & 7) << 5) | (bid >> 3);   // 0..255 bijection
    const int col0   = colgrp * 16;
    const int lane = tid & 63;
    const int wave = tid >> 6;                    // 0..15
    const int c    = tid & 15;
    const int r    = tid >> 4;                    // 0..63 (gather group)
    const int col  = col0 + c;

    // stage w_rec rows [0,2048) for our 16 cols into LDS (fp32, stride 18)
    {
        const int srow = tid >> 2;                // 0..255
        const int c4   = (tid & 3) << 2;          // 0,4,8,12
#pragma unroll
        for (int pass = 0; pass < 8; ++pass) {
            const int row = pass * 256 + srow;
            const float4 q = *(const float4*)(w_rec + (size_t)row * NN + col0 + c4);
            float2* dst = (float2*)(wlds + row * WSTRIDE + c4);  // 8B-aligned always
            dst[0] = make_float2(q.x, q.y);
            dst[1] = make_float2(q.z, q.w);
        }
    }
    __syncthreads();

    float v = 0.0f, tv = 1.0f;
    int sprev = 0;
    const float* wrc = w_rec + col + (size_t)(r << 6) * NN;  // groups r>=32: rows>=2048
    const int ldsbase = (r << 6) * WSTRIDE + c;              // groups r<32: LDS rows
    unsigned int* myrep = maskrep + ((bid & 15) * 2) * 256;

    float xreg = 0.0f;
    if (tid < 16) xreg = X[col];                  // X[t=0][col]

    for (int t = 0; t < TT; ++t) {
        // wave0: spin on own replica until all 256 tags == t, then LDS-broadcast
        if (wave == 0) {
            const uint4* pp = (const uint4*)(myrep + (t & 1) * 256) + lane;
            const unsigned int ut = (unsigned int)t;
            uint4 q;
            for (;;) {
                q = llc_load_v4(pp);
                unsigned int bad = ((q.x >> 16) ^ ut) | ((q.y >> 16) ^ ut)
                                 | ((q.z >> 16) ^ ut) | ((q.w >> 16) ^ ut);
                if (__all(bad == 0u)) break;
            }
            ((uint4*)mask_sh)[lane] = q;
        }
        __syncthreads();                          // S: masks ready in LDS

        unsigned long long M;
        {
            const unsigned int* ms = mask_sh + (r << 2);
            M = ((unsigned long long)(ms[0] & 0xFFFFu))
              | ((unsigned long long)(ms[1] & 0xFFFFu) << 16)
              | ((unsigned long long)(ms[2] & 0xFFFFu) << 32)
              | ((unsigned long long)(ms[3] & 0xFFFFu) << 48);
        }
        float acc0 = 0.0f, acc1 = 0.0f, acc2 = 0.0f, acc3 = 0.0f;
        if (r < 32) {
            // LDS-resident rows: ~120cy latency, 4-deep
            while (M) {
                float l0, l1 = 0.0f, l2 = 0.0f, l3 = 0.0f;
                int b0 = __builtin_ctzll(M); M &= M - 1;
                l0 = wlds[ldsbase + b0 * WSTRIDE];
                if (M) { int b = __builtin_ctzll(M); M &= M - 1; l1 = wlds[ldsbase + b * WSTRIDE]; }
                if (M) { int b = __builtin_ctzll(M); M &= M - 1; l2 = wlds[ldsbase + b * WSTRIDE]; }
                if (M) { int b = __builtin_ctzll(M); M &= M - 1; l3 = wlds[ldsbase + b * WSTRIDE]; }
                acc0 += l0 + l2; acc1 += l1 + l3;
            }
        } else {
            // L2-resident rows: 16-deep ILP, typically one round
            while (M) {
                float l0,        l1 = 0.0f, l2 = 0.0f, l3 = 0.0f,
                      l4 = 0.0f, l5 = 0.0f, l6 = 0.0f, l7 = 0.0f,
                      l8 = 0.0f, l9 = 0.0f, l10 = 0.0f, l11 = 0.0f,
                      l12 = 0.0f, l13 = 0.0f, l14 = 0.0f, l15 = 0.0f;
                int b0 = __builtin_ctzll(M); M &= M - 1;
                l0 = wrc[(size_t)b0 * NN];
                if (M) { int b = __builtin_ctzll(M); M &= M - 1; l1  = wrc[(size_t)b * NN]; }
                if (M) { int b = __builtin_ctzll(M); M &= M - 1; l2  = wrc[(size_t)b * NN]; }
                if (M) { int b = __builtin_ctzll(M); M &= M - 1; l3  = wrc[(size_t)b * NN]; }
                if (M) { int b = __builtin_ctzll(M); M &= M - 1; l4  = wrc[(size_t)b * NN]; }
                if (M) { int b = __builtin_ctzll(M); M &= M - 1; l5  = wrc[(size_t)b * NN]; }
                if (M) { int b = __builtin_ctzll(M); M &= M - 1; l6  = wrc[(size_t)b * NN]; }
                if (M) { int b = __builtin_ctzll(M); M &= M - 1; l7  = wrc[(size_t)b * NN]; }
                if (M) { int b = __builtin_ctzll(M); M &= M - 1; l8  = wrc[(size_t)b * NN]; }
                if (M) { int b = __builtin_ctzll(M); M &= M - 1; l9  = wrc[(size_t)b * NN]; }
                if (M) { int b = __builtin_ctzll(M); M &= M - 1; l10 = wrc[(size_t)b * NN]; }
                if (M) { int b = __builtin_ctzll(M); M &= M - 1; l11 = wrc[(size_t)b * NN]; }
                if (M) { int b = __builtin_ctzll(M); M &= M - 1; l12 = wrc[(size_t)b * NN]; }
                if (M) { int b = __builtin_ctzll(M); M &= M - 1; l13 = wrc[(size_t)b * NN]; }
                if (M) { int b = __builtin_ctzll(M); M &= M - 1; l14 = wrc[(size_t)b * NN]; }
                if (M) { int b = __builtin_ctzll(M); M &= M - 1; l15 = wrc[(size_t)b * NN]; }
                acc0 += l0 + l4;  acc1 += l1 + l5;  acc2 += l2 + l6;  acc3 += l3 + l7;
                acc0 += l8 + l12; acc1 += l9 + l13; acc2 += l10 + l14; acc3 += l11 + l15;
            }
        }
        // wave-internal pre-reduce across its 4 groups (lanes share c at xor 16/32)
        float part = (acc0 + acc1) + (acc2 + acc3);
        part += __shfl_xor(part, 16, 64);
        part += __shfl_xor(part, 32, 64);
        if (lane < 16) red_sh[wave * 17 + lane] = part;
        __syncthreads();                          // A: 16 wave-partials per col in LDS

        if (wave == 0) {
            const int cw = lane & 15, h = lane >> 4;        // h = 0..3
            const float* sp = red_sh + h * 4 * 17 + cw;
            float s = (sp[0] + sp[17]) + (sp[34] + sp[51]);
            s += __shfl_xor(s, 16, 64);
            s += __shfl_xor(s, 32, 64);

            bool spike = false;
            if (lane < 16) {
                float x = xreg + s;
                v *= DECAYF;
                if (sprev) x = 0.0f;              // refractory == spiked last step
                v += x;
                spike = v >= THRESHF;
                if (spike) { tv = (float)t * (1.0f / 300.0f); v = 0.0f; }
                sprev = spike ? 1 : 0;
            }
            unsigned long long bal = __ballot(spike);
            if (lane == 0) {
                unsigned int word = ((unsigned int)(t + 1) << 16)
                                  | (unsigned int)(bal & 0xFFFFull);
                const int par = (t + 1) & 1;
#pragma unroll
                for (int rep = 0; rep < NREP; ++rep)
                    __hip_atomic_store(maskrep + (rep * 2 + par) * 256 + colgrp, word,
                                       __ATOMIC_RELAXED, __HIP_MEMORY_SCOPE_AGENT);
            }
            if (lane < 16) {
                size_t o = (size_t)t * NN + col;
                s_all[o] = spike ? 1.0f : 0.0f;
                t_all[o] = tv;
                v_all[o] = v;
                if (t + 1 < TT) xreg = X[(size_t)(t + 1) * NN + col];  // off critical path
            }
        }
        // waves 1..15 proceed to S(t+1) and wait there (no memory traffic)
    }
}

extern "C" void kernel_launch(void* const* d_in, const int* in_sizes, int n_in,
                              void* d_out, int out_size, void* d_ws, size_t ws_size,
                              hipStream_t stream) {
    if (ws_size < WS_REQ) return;   // need ~10.5 MB scratch
    const int*   inp   = (const int*)d_in[0];
    const float* w     = (const float*)d_in[1];
    const float* w_rec = (const float*)d_in[2];
    float* out = (float*)d_out;
    float* ws  = (float*)d_ws;
    // 146 KiB dynamic LDS needs the opt-in attribute (host-side; capture-safe)
    hipFuncSetAttribute((const void*)lif_sim,
                        hipFuncAttributeMaxDynamicSharedMemorySize, DSM_BYTES);
    void* args[] = {(void*)&inp, (void*)&w, (void*)&w_rec, (void*)&out, (void*)&ws};
    hipLaunchCooperativeKernel((const void*)lif_sim, dim3(GRID), dim3(BLOCK),
                               args, DSM_BYTES, stream);
}